// Round 6
// baseline (384.705 us; speedup 1.0000x reference)
//
#include <hip/hip_runtime.h>
#include <cstdint>

// B=4, L=2048, H=512, HEADS=8, D=64.
// Only the DIAGONAL of softmax(scores) is consumed:
//   diag_i = exp(s_ii) / sum_j exp(s_ij),
//   s_ij = q_i.k_j + q_i.Wp[2047+j-i (padded)] + Wp_b[2047+j-i]
// Logits in log2 units (q pre-scaled by log2e/8 via prep-scaled Wq, bias by log2e).

typedef unsigned short u16;
typedef __bf16 bf16x8 __attribute__((ext_vector_type(8)));
typedef __bf16 bf16x2 __attribute__((ext_vector_type(2)));
typedef float  f32x16 __attribute__((ext_vector_type(16)));
typedef uint32_t __attribute__((address_space(1))) as1_u32;
typedef uint32_t __attribute__((address_space(3))) as3_u32;

__device__ __forceinline__ u16 f2bf(float f) {
  __bf16 h = (__bf16)f;
  return __builtin_bit_cast(u16, h);
}
__device__ __forceinline__ uint32_t pkbf(float a, float b) {
  bf16x2 v; v[0] = (__bf16)a; v[1] = (__bf16)b;
  return __builtin_bit_cast(uint32_t, v);
}
__device__ __forceinline__ float bf2f(u16 u) {
  return __uint_as_float(((uint32_t)u) << 16);
}
__device__ __forceinline__ float exp2v(float x) {
  float r;
  asm("v_exp_f32 %0, %1" : "=v"(r) : "v"(x));
  return r;
}
__device__ __forceinline__ void gl_lds16(const void* g, void* l) {
  __builtin_amdgcn_global_load_lds((const as1_u32*)g, (as3_u32*)l, 16, 0, 0);
}

// ---------------------------------------------------------------------------
// Prep: fp32 -> bf16 for q_in/k_in/v_in, Wq/Wk/Wv/Wo, Wp (padded to 4096 rows)
// Wq is pre-scaled by log2e/8 so the QKV epilogue needs no multiply.
// ---------------------------------------------------------------------------
__global__ __launch_bounds__(256) void prep_kernel(
    const float* __restrict__ qin, const float* __restrict__ kin, const float* __restrict__ vin,
    const float* __restrict__ wq,  const float* __restrict__ wk,  const float* __restrict__ wv,
    const float* __restrict__ wo,  const float* __restrict__ wp,
    u16* __restrict__ xq, u16* __restrict__ xk, u16* __restrict__ xv,
    u16* __restrict__ bwq, u16* __restrict__ bwk, u16* __restrict__ bwv,
    u16* __restrict__ bwo, u16* __restrict__ bwp) {
  long u = (long)blockIdx.x * 256 + threadIdx.x;
  const float* src; u16* dst; long off; float qs = 1.0f;
  if      (u < 524288L)  { src = qin; dst = xq;  off = u; }
  else if (u < 1048576L) { src = kin; dst = xk;  off = u - 524288L; }
  else if (u < 1572864L) { src = vin; dst = xv;  off = u - 1048576L; }
  else if (u < 1605632L) { src = wq;  dst = bwq; off = u - 1572864L; qs = 0.18033688f; }
  else if (u < 1638400L) { src = wk;  dst = bwk; off = u - 1605632L; }
  else if (u < 1671168L) { src = wv;  dst = bwv; off = u - 1638400L; }
  else if (u < 1703936L) { src = wo;  dst = bwo; off = u - 1671168L; }
  else if (u < 1736696L) { src = wp;  dst = bwp; off = u - 1703936L; }
  else {  // zero-fill Wp pad row 4095
    long o = (u - 1736696L) * 8 + 262080L;
    uint4 z = {0u, 0u, 0u, 0u};
    *(uint4*)(bwp + o) = z;
    return;
  }
  const float4* s4 = (const float4*)(src + off * 8);
  float4 a = s4[0], b = s4[1];
  uint32_t p0 = pkbf(a.x * qs, a.y * qs);
  uint32_t p1 = pkbf(a.z * qs, a.w * qs);
  uint32_t p2 = pkbf(b.x * qs, b.y * qs);
  uint32_t p3 = pkbf(b.z * qs, b.w * qs);
  uint4 o = {p0, p1, p2, p3};
  *(uint4*)(dst + off * 8) = o;
}

// ---------------------------------------------------------------------------
// 64x64-tile GEMM core (C = A @ W^T), 4 waves, each wave one 32x32 quadrant.
// ---------------------------------------------------------------------------
__device__ __forceinline__ void gemm64_core(
    const u16* __restrict__ A, const u16* __restrict__ W, int m0, int n0,
    u16* Al, u16* Bl, int tid, f32x16& acc) {
  const int lane = tid & 63, w = tid >> 6;
  const int wi = w >> 1, wj = w & 1;
  const int l31 = lane & 31, lh = lane >> 5;
  const int r = tid >> 2, ch = tid & 3;
  const int gch = ch ^ ((r >> 1) & 3);
  for (int kb = 0; kb < 16; ++kb) {
    gl_lds16(A + (long)(m0 + r) * 512 + kb * 32 + gch * 8, (char*)Al + w * 64 * 16);
    gl_lds16(W + (long)(n0 + r) * 512 + kb * 32 + gch * 8, (char*)Bl + w * 64 * 16);
    __syncthreads();
    bf16x8 af[2], bfr[2];
#pragma unroll
    for (int ks = 0; ks < 2; ++ks) {
      int c2 = 2 * ks + lh;
      int rA = 32 * wi + l31;
      int rB = 32 * wj + l31;
      af[ks]  = *(const bf16x8*)((char*)Al + (rA * 4 + (c2 ^ ((rA >> 1) & 3))) * 16);
      bfr[ks] = *(const bf16x8*)((char*)Bl + (rB * 4 + (c2 ^ ((rB >> 1) & 3))) * 16);
    }
#pragma unroll
    for (int ks = 0; ks < 2; ++ks)
      acc = __builtin_amdgcn_mfma_f32_32x32x16_bf16(af[ks], bfr[ks], acc, 0, 0, 0);
    __syncthreads();
  }
}

// gemm_bt: final projection, fp32 out row-major. 1024 blocks.
__global__ __launch_bounds__(256, 4) void gemm_bt(
    const u16* __restrict__ A, const u16* __restrict__ W, const float* __restrict__ bias,
    float* __restrict__ ofp) {
  __shared__ u16 Al[64 * 32];
  __shared__ u16 Bl[64 * 32];
  const int tid = threadIdx.x;
  const int lane = tid & 63, w = tid >> 6;
  const int wi = w >> 1, wj = w & 1;
  const int l31 = lane & 31, lh = lane >> 5;
  const int u = (blockIdx.x & 7) * 128 + (blockIdx.x >> 3);
  const int m0 = (u >> 3) * 64, n0 = (u & 7) * 64;

  float bv = bias[n0 + 32 * wj + l31];
  f32x16 acc;
#pragma unroll
  for (int rr = 0; rr < 16; ++rr) acc[rr] = bv;

  gemm64_core(A, W, m0, n0, Al, Bl, tid, acc);

  int n = n0 + 32 * wj + l31;
#pragma unroll
  for (int rr = 0; rr < 16; ++rr) {
    int row = m0 + 32 * wi + (rr & 3) + 8 * (rr >> 2) + 4 * lh;
    ofp[(long)row * 512 + n] = acc[rr];
  }
}

// qkv_gemm: 3072 blocks (3 mats x 1024), bf16 out in (b,h,l,d).
__global__ __launch_bounds__(256, 4) void qkv_gemm(
    const u16* __restrict__ xq, const u16* __restrict__ xk, const u16* __restrict__ xv,
    const u16* __restrict__ wqp, const u16* __restrict__ wkp, const u16* __restrict__ wvp,
    const float* __restrict__ bq, const float* __restrict__ bk, const float* __restrict__ bv,
    u16* __restrict__ oq, u16* __restrict__ ok, u16* __restrict__ ov) {
  __shared__ u16 Al[64 * 32];
  __shared__ u16 Bl[64 * 32];
  const int mat = blockIdx.x >> 10;
  const int t = blockIdx.x & 1023;
  const u16* A = (mat == 0) ? xq : (mat == 1) ? xk : xv;
  const u16* W = (mat == 0) ? wqp : (mat == 1) ? wkp : wvp;
  const float* bias = (mat == 0) ? bq : (mat == 1) ? bk : bv;
  u16* obf = (mat == 0) ? oq : (mat == 1) ? ok : ov;
  const float bsc = (mat == 0) ? 0.18033688f : 1.0f;

  const int tid = threadIdx.x;
  const int lane = tid & 63, w = tid >> 6;
  const int wi = w >> 1, wj = w & 1;
  const int l31 = lane & 31, lh = lane >> 5;
  const int u = (t & 7) * 128 + (t >> 3);
  const int m0 = (u >> 3) * 64, n0 = (u & 7) * 64;

  float bvv = bias[n0 + 32 * wj + l31] * bsc;
  f32x16 acc;
#pragma unroll
  for (int rr = 0; rr < 16; ++rr) acc[rr] = bvv;

  gemm64_core(A, W, m0, n0, Al, Bl, tid, acc);

  int n = n0 + 32 * wj + l31;
  int h = n >> 6, d = n & 63;
#pragma unroll
  for (int rr = 0; rr < 16; ++rr) {
    int row = m0 + 32 * wi + (rr & 3) + 8 * (rr >> 2) + 4 * lh;
    int b = row >> 11, l = row & 2047;
    obf[(((long)(b * 8 + h)) * 2048 + l) * 64 + d] = f2bf(acc[rr]);
  }
}

// ---------------------------------------------------------------------------
// Attention v6: barrier-free, bf16-PACKED rolling P tiles (8 u32 per tile
// instead of 16 f32) to cut total VGPR+AGPR below 128/wave -> 4 waves/SIMD.
// 2048 blocks: (b,h, 64-row i-tile, column HALF); wave (wi,wj) owns rows
// [r0,r0+32) x cols c0=1024*half+512*wj+32t, t=0..15.
// Per step: K loads issued at top (single-buffered, v4-proven spill-free);
// skew gather = per-reg {cndmask packed word (source-lane tsel>=31-lrr),
// ds_bpermute, lo/hi bf16 extract} -> accS C-init; 4-MFMA score chain; P tile
// t+2 MFMA chain + cvt_pk pack overwrites the retired 8-word buffer; exp2.
// Carried regs: aq 16 + pa 8 + pb 8 + rsum 16 = 48 (+transients ~60).
// Window math: W(j,r)=2047+j-r; wb=2016+c0-r0; idx=31+l31-lrr-4lh in [0,62];
// max Wp row touched = 4095 (zero pad row), bias clamp 4094 (never read).
// ---------------------------------------------------------------------------
#define PTILE(G, XP)                                                             \
  do {                                                                           \
    int wr_ = wb + 32 * (G) + l31;                                               \
    const u16* bp_ = wpw + (long)wr_ * 64 + lh * 8;                              \
    bf16x8 bw0 = *(const bf16x8*)(bp_);                                          \
    bf16x8 bw1 = *(const bf16x8*)(bp_ + 16);                                     \
    bf16x8 bw2 = *(const bf16x8*)(bp_ + 32);                                     \
    bf16x8 bw3 = *(const bf16x8*)(bp_ + 48);                                     \
    float bv_ = wpb[wr_ > 4094 ? 4094 : wr_] * 1.44269504f;                      \
    f32x16 accP;                                                                 \
    _Pragma("unroll")                                                            \
    for (int r = 0; r < 16; ++r) accP[r] = bv_;                                  \
    accP = __builtin_amdgcn_mfma_f32_32x32x16_bf16(aq0, bw0, accP, 0, 0, 0);     \
    accP = __builtin_amdgcn_mfma_f32_32x32x16_bf16(aq1, bw1, accP, 0, 0, 0);     \
    accP = __builtin_amdgcn_mfma_f32_32x32x16_bf16(aq2, bw2, accP, 0, 0, 0);     \
    accP = __builtin_amdgcn_mfma_f32_32x32x16_bf16(aq3, bw3, accP, 0, 0, 0);     \
    _Pragma("unroll")                                                            \
    for (int i = 0; i < 8; ++i) XP[i] = pkbf(accP[2 * i], accP[2 * i + 1]);      \
  } while (0)

#define ATTN_STEP(T, XP, YP, DO_NEXT)                                            \
  do {                                                                           \
    const int t_ = (T);                                                          \
    const u16* kp_ = kb + (long)(c0 + 32 * t_ + l31) * 64 + lh * 8;              \
    bf16x8 kf0 = *(const bf16x8*)(kp_);                                          \
    bf16x8 kf1 = *(const bf16x8*)(kp_ + 16);                                     \
    bf16x8 kf2 = *(const bf16x8*)(kp_ + 32);                                     \
    bf16x8 kf3 = *(const bf16x8*)(kp_ + 48);                                     \
    f32x16 accS;                                                                 \
    _Pragma("unroll")                                                            \
    for (int r = 0; r < 16; ++r) {                                               \
      const int lrr = (r & 3) + 8 * (r >> 2);                                    \
      uint32_t sel = (tsel >= 31 - lrr) ? XP[r >> 1] : YP[r >> 1];               \
      int gi = __builtin_amdgcn_ds_bpermute((((lbb - lrr) & 31) << 2) + hb,      \
                                            (int)sel);                           \
      uint32_t gv = (uint32_t)gi;                                                \
      accS[r] = __uint_as_float((r & 1) ? (gv & 0xffff0000u) : (gv << 16));      \
    }                                                                            \
    accS = __builtin_amdgcn_mfma_f32_32x32x16_bf16(aq0, kf0, accS, 0, 0, 0);     \
    accS = __builtin_amdgcn_mfma_f32_32x32x16_bf16(aq1, kf1, accS, 0, 0, 0);     \
    accS = __builtin_amdgcn_mfma_f32_32x32x16_bf16(aq2, kf2, accS, 0, 0, 0);     \
    accS = __builtin_amdgcn_mfma_f32_32x32x16_bf16(aq3, kf3, accS, 0, 0, 0);     \
    if (DO_NEXT) { PTILE(t_ + 2, XP); }                                          \
    _Pragma("unroll")                                                            \
    for (int r = 0; r < 16; ++r) rsum[r] += exp2v(accS[r]);                      \
    if (t_ == td) {                                                              \
      _Pragma("unroll")                                                          \
      for (int r = 0; r < 16; ++r) {                                             \
        const int lrr = (r & 3) + 8 * (r >> 2);                                  \
        if (l31 == lrr + 4 * lh) pdiag[tb64 + 32 * wi + l31] = accS[r];          \
      }                                                                          \
    }                                                                            \
  } while (0)

__global__ __launch_bounds__(256, 4) void attn_kernel(
    const u16* __restrict__ qw, const u16* __restrict__ kw,
    const u16* __restrict__ wpw, const float* __restrict__ wpb,
    float* __restrict__ psum, float* __restrict__ pdiag) {
  __shared__ float rssum[128];

  const int tid = threadIdx.x, lane = tid & 63, w = tid >> 6;
  const int wi = w >> 1, wj = w & 1;
  // XCD swizzle: 2048 blocks; XCD x gets bh in {x, x+8, x+16, x+24}.
  const int sbi = blockIdx.x;
  const int x = sbi & 7, g = sbi >> 3;          // g in 0..255
  const int bh = x + 8 * (g >> 6);
  const int rem = g & 63;
  const int it = rem >> 1, half = rem & 1;
  const int i0 = it * 64;
  const u16* qb = qw + (long)bh * 2048 * 64;
  const u16* kb = kw + (long)bh * 2048 * 64;

  const int l31 = lane & 31, lh = lane >> 5;
  const int r0 = i0 + 32 * wi;
  const int c0 = 1024 * half + 512 * wj;
  const int wb = 2016 + c0 - r0;               // window base at t=0
  const int tsel = l31 + 4 * lh;               // A/B select key (source lane)
  const int lbb = l31 + 31 - 4 * lh;           // bpermute index base
  const int hb = 128 * lh;                     // byte base of this 32-half
  const long tb64 = (long)(bh * 32 + it) * 64;

  // A-fragments: Q rows r0 + l31, full K=64 (log2e/8 pre-scaled)
  bf16x8 aq0, aq1, aq2, aq3;
  {
    const u16* p = qb + (long)(r0 + l31) * 64 + lh * 8;
    aq0 = *(const bf16x8*)(p);
    aq1 = *(const bf16x8*)(p + 16);
    aq2 = *(const bf16x8*)(p + 32);
    aq3 = *(const bf16x8*)(p + 48);
  }

  float rsum[16];
#pragma unroll
  for (int r = 0; r < 16; ++r) rsum[r] = 0.f;

  int td = -1;  // step holding this wave's diagonal (if any)
  {
    int tdn = r0 - c0;
    if (tdn >= 0 && tdn < 512) td = tdn >> 5;
  }

  // prologue: packed window tiles 0 and 1
  uint32_t pa[8], pb[8];
  PTILE(0, pa);
  PTILE(1, pb);

  // main loop: 16 steps; 2-unrolled for static buffer parity.
  // step t: gather from (tile t, tile t+1); tile t+2 overwrites slot of t.
  for (int tt = 0; tt < 14; tt += 2) {
    ATTN_STEP(tt,     pa, pb, true);   // pa <- tile tt+2
    ATTN_STEP(tt + 1, pb, pa, true);   // pb <- tile tt+3
  }
  ATTN_STEP(14, pa, pb, true);         // pa <- tile 16
  ATTN_STEP(15, pb, pa, false);

  // reduce row partials across the 32 lanes sharing each row
#pragma unroll
  for (int r = 0; r < 16; ++r) {
    float v = rsum[r];
    v += __shfl_xor(v, 1);
    v += __shfl_xor(v, 2);
    v += __shfl_xor(v, 4);
    v += __shfl_xor(v, 8);
    v += __shfl_xor(v, 16);
    rsum[r] = v;
  }
  if (l31 == 0) {
#pragma unroll
    for (int r = 0; r < 16; ++r) {
      int lr = (r & 3) + 8 * (r >> 2) + 4 * lh;
      rssum[(32 * wi + lr) * 2 + wj] = rsum[r];
    }
  }
  __syncthreads();
  if (tid < 64) {
    float S = rssum[2 * tid] + rssum[2 * tid + 1];
    psum[(tb64 * 2) + half * 64 + tid] = S;   // ((bh*32+it)*2 + half)*64 + row
  }
}

// ---------------------------------------------------------------------------
// Combine: attw = exp2(diag) / (psum_half0 + psum_half1); out_pre = attw * v.
// 1024 blocks x 256 threads; each block one (bh, 64-row i-tile).
// ---------------------------------------------------------------------------
__global__ __launch_bounds__(256) void combine_kernel(
    const u16* __restrict__ vw, const float* __restrict__ psum,
    const float* __restrict__ pdiag, u16* __restrict__ outp) {
  const int u = blockIdx.x;            // bh*32 + it
  const int bh = u >> 5, it = u & 31, i0 = it * 64;
  const int tid = threadIdx.x;
  const int r = tid >> 2, dd = (tid & 3) * 16;
  float S = psum[u * 128 + r] + psum[u * 128 + 64 + r];
  float a = exp2v(pdiag[u * 64 + r]) / S;
  const int b = bh >> 3, h = bh & 7;
  const u16* vp = vw + (long)bh * 2048 * 64 + (long)(i0 + r) * 64 + dd;
  u16* op = outp + ((long)(b * 2048 + i0 + r)) * 512 + h * 64 + dd;
  uint4 v0 = *(const uint4*)vp;
  uint4 v1 = *(const uint4*)(vp + 8);
  uint32_t vin[8] = {v0.x, v0.y, v0.z, v0.w, v1.x, v1.y, v1.z, v1.w};
  uint32_t vout[8];
#pragma unroll
  for (int e = 0; e < 8; ++e) {
    float lo = bf2f((u16)(vin[e] & 0xffffu)) * a;
    float hi = bf2f((u16)(vin[e] >> 16)) * a;
    vout[e] = pkbf(lo, hi);
  }
  uint4 o0 = {vout[0], vout[1], vout[2], vout[3]};
  uint4 o1 = {vout[4], vout[5], vout[6], vout[7]};
  *(uint4*)op = o0;
  *(uint4*)(op + 8) = o1;
}

// ---------------------------------------------------------------------------
extern "C" void kernel_launch(void* const* d_in, const int* in_sizes, int n_in,
                              void* d_out, int out_size, void* d_ws, size_t ws_size,
                              hipStream_t stream) {
  (void)in_sizes; (void)n_in; (void)out_size; (void)ws_size;
  const float* q_in = (const float*)d_in[0];
  const float* k_in = (const float*)d_in[1];
  const float* v_in = (const float*)d_in[2];
  const float* Wq_w = (const float*)d_in[3];
  const float* Wq_b = (const float*)d_in[4];
  const float* Wk_w = (const float*)d_in[5];
  const float* Wk_b = (const float*)d_in[6];
  const float* Wv_w = (const float*)d_in[7];
  const float* Wv_b = (const float*)d_in[8];
  const float* Wo_w = (const float*)d_in[9];
  const float* Wo_b = (const float*)d_in[10];
  const float* Wp_w = (const float*)d_in[11];
  const float* Wp_b = (const float*)d_in[12];

  char* ws = (char*)d_ws;
  u16* xq    = (u16*)(ws + 0);         // 8 MB  bf16 q_in
  u16* xk    = (u16*)(ws + 8388608);   // 8 MB
  u16* xv    = (u16*)(ws + 16777216);  // 8 MB
  u16* wq    = (u16*)(ws + 25165824);  // 512 KB each
  u16* wk    = (u16*)(ws + 25690112);
  u16* wv    = (u16*)(ws + 26214400);
  u16* wo    = (u16*)(ws + 26738688);
  u16* wp    = (u16*)(ws + 27262976);  // 4096x64 bf16 (row 4095 zero)
  u16* q_ws  = (u16*)(ws + 27787264);  // (b,h,l,d) bf16, pre-scaled log2e/8
  u16* k_ws  = (u16*)(ws + 36175872);
  u16* v_ws  = (u16*)(ws + 44564480);
  u16* opre  = (u16*)(ws + 52953088);  // (b*l, h*d) bf16 diag-scaled v
  float* psum  = (float*)(ws + 61341696);  // 1024 x 2 x 64 f32 partial sums
  float* pdiag = (float*)(ws + 61865984);  // 1024 x 64 f32 diagonal logits

  prep_kernel<<<6784, 256, 0, stream>>>(q_in, k_in, v_in, Wq_w, Wk_w, Wv_w, Wo_w, Wp_w,
                                        xq, xk, xv, wq, wk, wv, wo, wp);
  qkv_gemm<<<3072, 256, 0, stream>>>(xq, xk, xv, wq, wk, wv, Wq_b, Wk_b, Wv_b,
                                     q_ws, k_ws, v_ws);
  attn_kernel<<<2048, 256, 0, stream>>>(q_ws, k_ws, wp, Wp_b, psum, pdiag);
  combine_kernel<<<1024, 256, 0, stream>>>(v_ws, psum, pdiag, opre);
  gemm_bt<<<1024, 256, 0, stream>>>(opre, wo, Wo_b, (float*)d_out);
}

// Round 7
// 283.511 us; speedup vs baseline: 1.3569x; 1.3569x over previous
//
#include <hip/hip_runtime.h>
#include <cstdint>

// B=4, L=2048, H=512, HEADS=8, D=64.
// Only the DIAGONAL of softmax(scores) is consumed:
//   diag_i = exp(s_ii) / sum_j exp(s_ij),
//   s_ij = q_i.k_j + q_i.Wp[2047+j-i (padded)] + Wp_b[2047+j-i]
// Logits in log2 units (q pre-scaled by log2e/8 via prep-scaled Wq, bias by log2e).

typedef unsigned short u16;
typedef __bf16 bf16x8 __attribute__((ext_vector_type(8)));
typedef __bf16 bf16x2 __attribute__((ext_vector_type(2)));
typedef float  f32x16 __attribute__((ext_vector_type(16)));
typedef uint32_t __attribute__((address_space(1))) as1_u32;
typedef uint32_t __attribute__((address_space(3))) as3_u32;

__device__ __forceinline__ u16 f2bf(float f) {
  __bf16 h = (__bf16)f;
  return __builtin_bit_cast(u16, h);
}
__device__ __forceinline__ uint32_t pkbf(float a, float b) {
  bf16x2 v; v[0] = (__bf16)a; v[1] = (__bf16)b;
  return __builtin_bit_cast(uint32_t, v);
}
__device__ __forceinline__ float bf2f(u16 u) {
  return __uint_as_float(((uint32_t)u) << 16);
}
__device__ __forceinline__ float exp2v(float x) {
  float r;
  asm("v_exp_f32 %0, %1" : "=v"(r) : "v"(x));
  return r;
}
__device__ __forceinline__ void gl_lds16(const void* g, void* l) {
  __builtin_amdgcn_global_load_lds((const as1_u32*)g, (as3_u32*)l, 16, 0, 0);
}

// ---------------------------------------------------------------------------
// Prep: fp32 -> bf16 for q_in/k_in/v_in, Wq/Wk/Wv/Wo, Wp (padded to 4096 rows)
// Wq is pre-scaled by log2e/8 so the QKV epilogue needs no multiply.
// ---------------------------------------------------------------------------
__global__ __launch_bounds__(256) void prep_kernel(
    const float* __restrict__ qin, const float* __restrict__ kin, const float* __restrict__ vin,
    const float* __restrict__ wq,  const float* __restrict__ wk,  const float* __restrict__ wv,
    const float* __restrict__ wo,  const float* __restrict__ wp,
    u16* __restrict__ xq, u16* __restrict__ xk, u16* __restrict__ xv,
    u16* __restrict__ bwq, u16* __restrict__ bwk, u16* __restrict__ bwv,
    u16* __restrict__ bwo, u16* __restrict__ bwp) {
  long u = (long)blockIdx.x * 256 + threadIdx.x;
  const float* src; u16* dst; long off; float qs = 1.0f;
  if      (u < 524288L)  { src = qin; dst = xq;  off = u; }
  else if (u < 1048576L) { src = kin; dst = xk;  off = u - 524288L; }
  else if (u < 1572864L) { src = vin; dst = xv;  off = u - 1048576L; }
  else if (u < 1605632L) { src = wq;  dst = bwq; off = u - 1572864L; qs = 0.18033688f; }
  else if (u < 1638400L) { src = wk;  dst = bwk; off = u - 1605632L; }
  else if (u < 1671168L) { src = wv;  dst = bwv; off = u - 1638400L; }
  else if (u < 1703936L) { src = wo;  dst = bwo; off = u - 1671168L; }
  else if (u < 1736696L) { src = wp;  dst = bwp; off = u - 1703936L; }
  else {  // zero-fill Wp pad row 4095
    long o = (u - 1736696L) * 8 + 262080L;
    uint4 z = {0u, 0u, 0u, 0u};
    *(uint4*)(bwp + o) = z;
    return;
  }
  const float4* s4 = (const float4*)(src + off * 8);
  float4 a = s4[0], b = s4[1];
  uint32_t p0 = pkbf(a.x * qs, a.y * qs);
  uint32_t p1 = pkbf(a.z * qs, a.w * qs);
  uint32_t p2 = pkbf(b.x * qs, b.y * qs);
  uint32_t p3 = pkbf(b.z * qs, b.w * qs);
  uint4 o = {p0, p1, p2, p3};
  *(uint4*)(dst + off * 8) = o;
}

// ---------------------------------------------------------------------------
// 64x64-tile GEMM core (C = A @ W^T), 4 waves, each wave one 32x32 quadrant.
// ---------------------------------------------------------------------------
__device__ __forceinline__ void gemm64_core(
    const u16* __restrict__ A, const u16* __restrict__ W, int m0, int n0,
    u16* Al, u16* Bl, int tid, f32x16& acc) {
  const int lane = tid & 63, w = tid >> 6;
  const int wi = w >> 1, wj = w & 1;
  const int l31 = lane & 31, lh = lane >> 5;
  const int r = tid >> 2, ch = tid & 3;
  const int gch = ch ^ ((r >> 1) & 3);
  for (int kb = 0; kb < 16; ++kb) {
    gl_lds16(A + (long)(m0 + r) * 512 + kb * 32 + gch * 8, (char*)Al + w * 64 * 16);
    gl_lds16(W + (long)(n0 + r) * 512 + kb * 32 + gch * 8, (char*)Bl + w * 64 * 16);
    __syncthreads();
    bf16x8 af[2], bfr[2];
#pragma unroll
    for (int ks = 0; ks < 2; ++ks) {
      int c2 = 2 * ks + lh;
      int rA = 32 * wi + l31;
      int rB = 32 * wj + l31;
      af[ks]  = *(const bf16x8*)((char*)Al + (rA * 4 + (c2 ^ ((rA >> 1) & 3))) * 16);
      bfr[ks] = *(const bf16x8*)((char*)Bl + (rB * 4 + (c2 ^ ((rB >> 1) & 3))) * 16);
    }
#pragma unroll
    for (int ks = 0; ks < 2; ++ks)
      acc = __builtin_amdgcn_mfma_f32_32x32x16_bf16(af[ks], bfr[ks], acc, 0, 0, 0);
    __syncthreads();
  }
}

// gemm_bt: final projection, fp32 out row-major. 1024 blocks.
__global__ __launch_bounds__(256, 4) void gemm_bt(
    const u16* __restrict__ A, const u16* __restrict__ W, const float* __restrict__ bias,
    float* __restrict__ ofp) {
  __shared__ u16 Al[64 * 32];
  __shared__ u16 Bl[64 * 32];
  const int tid = threadIdx.x;
  const int lane = tid & 63, w = tid >> 6;
  const int wi = w >> 1, wj = w & 1;
  const int l31 = lane & 31, lh = lane >> 5;
  const int u = (blockIdx.x & 7) * 128 + (blockIdx.x >> 3);
  const int m0 = (u >> 3) * 64, n0 = (u & 7) * 64;

  float bv = bias[n0 + 32 * wj + l31];
  f32x16 acc;
#pragma unroll
  for (int rr = 0; rr < 16; ++rr) acc[rr] = bv;

  gemm64_core(A, W, m0, n0, Al, Bl, tid, acc);

  int n = n0 + 32 * wj + l31;
#pragma unroll
  for (int rr = 0; rr < 16; ++rr) {
    int row = m0 + 32 * wi + (rr & 3) + 8 * (rr >> 2) + 4 * lh;
    ofp[(long)row * 512 + n] = acc[rr];
  }
}

// qkv_gemm: 3072 blocks (3 mats x 1024), bf16 out in (b,h,l,d).
__global__ __launch_bounds__(256, 4) void qkv_gemm(
    const u16* __restrict__ xq, const u16* __restrict__ xk, const u16* __restrict__ xv,
    const u16* __restrict__ wqp, const u16* __restrict__ wkp, const u16* __restrict__ wvp,
    const float* __restrict__ bq, const float* __restrict__ bk, const float* __restrict__ bv,
    u16* __restrict__ oq, u16* __restrict__ ok, u16* __restrict__ ov) {
  __shared__ u16 Al[64 * 32];
  __shared__ u16 Bl[64 * 32];
  const int mat = blockIdx.x >> 10;
  const int t = blockIdx.x & 1023;
  const u16* A = (mat == 0) ? xq : (mat == 1) ? xk : xv;
  const u16* W = (mat == 0) ? wqp : (mat == 1) ? wkp : wvp;
  const float* bias = (mat == 0) ? bq : (mat == 1) ? bk : bv;
  u16* obf = (mat == 0) ? oq : (mat == 1) ? ok : ov;
  const float bsc = (mat == 0) ? 0.18033688f : 1.0f;

  const int tid = threadIdx.x;
  const int lane = tid & 63, w = tid >> 6;
  const int wi = w >> 1, wj = w & 1;
  const int l31 = lane & 31, lh = lane >> 5;
  const int u = (t & 7) * 128 + (t >> 3);
  const int m0 = (u >> 3) * 64, n0 = (u & 7) * 64;

  float bvv = bias[n0 + 32 * wj + l31] * bsc;
  f32x16 acc;
#pragma unroll
  for (int rr = 0; rr < 16; ++rr) acc[rr] = bvv;

  gemm64_core(A, W, m0, n0, Al, Bl, tid, acc);

  int n = n0 + 32 * wj + l31;
  int h = n >> 6, d = n & 63;
#pragma unroll
  for (int rr = 0; rr < 16; ++rr) {
    int row = m0 + 32 * wi + (rr & 3) + 8 * (rr >> 2) + 4 * lh;
    int b = row >> 11, l = row & 2047;
    obf[(((long)(b * 8 + h)) * 2048 + l) * 64 + d] = f2bf(acc[rr]);
  }
}

// ---------------------------------------------------------------------------
// Attention v7: v6 semantics (passed), PHASE-DISJOINT ordering so register
// live-sets never overlap -> no spill at the (256,4) 128-reg cap.
// Step phases: [kf loads -> gather(pa,pb) -> S-MFMA (kf dies) -> diag ->
// exp (accS dies)] then [bw loads -> P-MFMA -> cvt_pk pack into the buffer
// retired by this step's gather]. Peak live ~90-100 regs per phase.
// 2048 blocks: (b,h, 64-row i-tile, column HALF); wave (wi,wj) owns rows
// [r0,r0+32) x cols c0=1024*half+512*wj+32t, t=0..15. P tiles carried PACKED
// bf16 (8 u32 each). 4 waves/SIMD does the latency hiding (TLP, not in-step
// overlap). Partial row-sums -> psum; diagonal -> pdiag; combine kernel after.
// Window math: W(j,r)=2047+j-r; wb=2016+c0-r0; idx=31+l31-lrr-4lh in [0,62];
// max Wp row touched = 4095 (zero pad row), bias clamp 4094 (never read).
// ---------------------------------------------------------------------------
#define PTILE(G, XP)                                                             \
  do {                                                                           \
    int wr_ = wb + 32 * (G) + l31;                                               \
    const u16* bp_ = wpw + (long)wr_ * 64 + lh * 8;                              \
    bf16x8 bw0 = *(const bf16x8*)(bp_);                                          \
    bf16x8 bw1 = *(const bf16x8*)(bp_ + 16);                                     \
    bf16x8 bw2 = *(const bf16x8*)(bp_ + 32);                                     \
    bf16x8 bw3 = *(const bf16x8*)(bp_ + 48);                                     \
    float bv_ = wpb[wr_ > 4094 ? 4094 : wr_] * 1.44269504f;                      \
    f32x16 accP;                                                                 \
    _Pragma("unroll")                                                            \
    for (int r = 0; r < 16; ++r) accP[r] = bv_;                                  \
    accP = __builtin_amdgcn_mfma_f32_32x32x16_bf16(aq0, bw0, accP, 0, 0, 0);     \
    accP = __builtin_amdgcn_mfma_f32_32x32x16_bf16(aq1, bw1, accP, 0, 0, 0);     \
    accP = __builtin_amdgcn_mfma_f32_32x32x16_bf16(aq2, bw2, accP, 0, 0, 0);     \
    accP = __builtin_amdgcn_mfma_f32_32x32x16_bf16(aq3, bw3, accP, 0, 0, 0);     \
    _Pragma("unroll")                                                            \
    for (int i = 0; i < 8; ++i) XP[i] = pkbf(accP[2 * i], accP[2 * i + 1]);      \
  } while (0)

#define ATTN_STEP(T, XP, YP, DO_NEXT)                                            \
  do {                                                                           \
    const int t_ = (T);                                                          \
    const u16* kp_ = kb + (long)(c0 + 32 * t_ + l31) * 64 + lh * 8;              \
    bf16x8 kf0 = *(const bf16x8*)(kp_);                                          \
    bf16x8 kf1 = *(const bf16x8*)(kp_ + 16);                                     \
    bf16x8 kf2 = *(const bf16x8*)(kp_ + 32);                                     \
    bf16x8 kf3 = *(const bf16x8*)(kp_ + 48);                                     \
    f32x16 accS;                                                                 \
    _Pragma("unroll")                                                            \
    for (int r = 0; r < 16; ++r) {                                               \
      const int lrr = (r & 3) + 8 * (r >> 2);                                    \
      uint32_t sel = (tsel >= 31 - lrr) ? XP[r >> 1] : YP[r >> 1];               \
      int gi = __builtin_amdgcn_ds_bpermute((((lbb - lrr) & 31) << 2) + hb,      \
                                            (int)sel);                           \
      uint32_t gv = (uint32_t)gi;                                                \
      accS[r] = __uint_as_float((r & 1) ? (gv & 0xffff0000u) : (gv << 16));      \
    }                                                                            \
    accS = __builtin_amdgcn_mfma_f32_32x32x16_bf16(aq0, kf0, accS, 0, 0, 0);     \
    accS = __builtin_amdgcn_mfma_f32_32x32x16_bf16(aq1, kf1, accS, 0, 0, 0);     \
    accS = __builtin_amdgcn_mfma_f32_32x32x16_bf16(aq2, kf2, accS, 0, 0, 0);     \
    accS = __builtin_amdgcn_mfma_f32_32x32x16_bf16(aq3, kf3, accS, 0, 0, 0);     \
    if (t_ == td) {                                                              \
      _Pragma("unroll")                                                          \
      for (int r = 0; r < 16; ++r) {                                             \
        const int lrr = (r & 3) + 8 * (r >> 2);                                  \
        if (l31 == lrr + 4 * lh) pdiag[tb64 + 32 * wi + l31] = accS[r];          \
      }                                                                          \
    }                                                                            \
    _Pragma("unroll")                                                            \
    for (int r = 0; r < 16; ++r) rsum[r] += exp2v(accS[r]);                      \
    if (DO_NEXT) { PTILE(t_ + 2, XP); }                                          \
  } while (0)

__global__ __launch_bounds__(256, 4) void attn_kernel(
    const u16* __restrict__ qw, const u16* __restrict__ kw,
    const u16* __restrict__ wpw, const float* __restrict__ wpb,
    float* __restrict__ psum, float* __restrict__ pdiag) {
  __shared__ float rssum[128];

  const int tid = threadIdx.x, lane = tid & 63, w = tid >> 6;
  const int wi = w >> 1, wj = w & 1;
  // XCD swizzle: 2048 blocks; XCD x gets bh in {x, x+8, x+16, x+24}.
  const int sbi = blockIdx.x;
  const int x = sbi & 7, g = sbi >> 3;          // g in 0..255
  const int bh = x + 8 * (g >> 6);
  const int rem = g & 63;
  const int it = rem >> 1, half = rem & 1;
  const int i0 = it * 64;
  const u16* qb = qw + (long)bh * 2048 * 64;
  const u16* kb = kw + (long)bh * 2048 * 64;

  const int l31 = lane & 31, lh = lane >> 5;
  const int r0 = i0 + 32 * wi;
  const int c0 = 1024 * half + 512 * wj;
  const int wb = 2016 + c0 - r0;               // window base at t=0
  const int tsel = l31 + 4 * lh;               // A/B select key (source lane)
  const int lbb = l31 + 31 - 4 * lh;           // bpermute index base
  const int hb = 128 * lh;                     // byte base of this 32-half
  const long tb64 = (long)(bh * 32 + it) * 64;

  // A-fragments: Q rows r0 + l31, full K=64 (log2e/8 pre-scaled)
  bf16x8 aq0, aq1, aq2, aq3;
  {
    const u16* p = qb + (long)(r0 + l31) * 64 + lh * 8;
    aq0 = *(const bf16x8*)(p);
    aq1 = *(const bf16x8*)(p + 16);
    aq2 = *(const bf16x8*)(p + 32);
    aq3 = *(const bf16x8*)(p + 48);
  }

  float rsum[16];
#pragma unroll
  for (int r = 0; r < 16; ++r) rsum[r] = 0.f;

  int td = -1;  // step holding this wave's diagonal (if any)
  {
    int tdn = r0 - c0;
    if (tdn >= 0 && tdn < 512) td = tdn >> 5;
  }

  // prologue: packed window tiles 0 and 1
  uint32_t pa[8], pb[8];
  PTILE(0, pa);
  PTILE(1, pb);

  // main loop: 16 steps; 2-unrolled for static buffer parity.
  // step t: gather from (tile t, tile t+1); tile t+2 overwrites slot of t.
  for (int tt = 0; tt < 14; tt += 2) {
    ATTN_STEP(tt,     pa, pb, true);   // pa <- tile tt+2
    ATTN_STEP(tt + 1, pb, pa, true);   // pb <- tile tt+3
  }
  ATTN_STEP(14, pa, pb, true);         // pa <- tile 16
  ATTN_STEP(15, pb, pa, false);

  // reduce row partials across the 32 lanes sharing each row
#pragma unroll
  for (int r = 0; r < 16; ++r) {
    float v = rsum[r];
    v += __shfl_xor(v, 1);
    v += __shfl_xor(v, 2);
    v += __shfl_xor(v, 4);
    v += __shfl_xor(v, 8);
    v += __shfl_xor(v, 16);
    rsum[r] = v;
  }
  if (l31 == 0) {
#pragma unroll
    for (int r = 0; r < 16; ++r) {
      int lr = (r & 3) + 8 * (r >> 2) + 4 * lh;
      rssum[(32 * wi + lr) * 2 + wj] = rsum[r];
    }
  }
  __syncthreads();
  if (tid < 64) {
    float S = rssum[2 * tid] + rssum[2 * tid + 1];
    psum[(tb64 * 2) + half * 64 + tid] = S;   // ((bh*32+it)*2 + half)*64 + row
  }
}

// ---------------------------------------------------------------------------
// Combine: attw = exp2(diag) / (psum_half0 + psum_half1); out_pre = attw * v.
// 1024 blocks x 256 threads; each block one (bh, 64-row i-tile).
// ---------------------------------------------------------------------------
__global__ __launch_bounds__(256) void combine_kernel(
    const u16* __restrict__ vw, const float* __restrict__ psum,
    const float* __restrict__ pdiag, u16* __restrict__ outp) {
  const int u = blockIdx.x;            // bh*32 + it
  const int bh = u >> 5, it = u & 31, i0 = it * 64;
  const int tid = threadIdx.x;
  const int r = tid >> 2, dd = (tid & 3) * 16;
  float S = psum[u * 128 + r] + psum[u * 128 + 64 + r];
  float a = exp2v(pdiag[u * 64 + r]) / S;
  const int b = bh >> 3, h = bh & 7;
  const u16* vp = vw + (long)bh * 2048 * 64 + (long)(i0 + r) * 64 + dd;
  u16* op = outp + ((long)(b * 2048 + i0 + r)) * 512 + h * 64 + dd;
  uint4 v0 = *(const uint4*)vp;
  uint4 v1 = *(const uint4*)(vp + 8);
  uint32_t vin[8] = {v0.x, v0.y, v0.z, v0.w, v1.x, v1.y, v1.z, v1.w};
  uint32_t vout[8];
#pragma unroll
  for (int e = 0; e < 8; ++e) {
    float lo = bf2f((u16)(vin[e] & 0xffffu)) * a;
    float hi = bf2f((u16)(vin[e] >> 16)) * a;
    vout[e] = pkbf(lo, hi);
  }
  uint4 o0 = {vout[0], vout[1], vout[2], vout[3]};
  uint4 o1 = {vout[4], vout[5], vout[6], vout[7]};
  *(uint4*)op = o0;
  *(uint4*)(op + 8) = o1;
}

// ---------------------------------------------------------------------------
extern "C" void kernel_launch(void* const* d_in, const int* in_sizes, int n_in,
                              void* d_out, int out_size, void* d_ws, size_t ws_size,
                              hipStream_t stream) {
  (void)in_sizes; (void)n_in; (void)out_size; (void)ws_size;
  const float* q_in = (const float*)d_in[0];
  const float* k_in = (const float*)d_in[1];
  const float* v_in = (const float*)d_in[2];
  const float* Wq_w = (const float*)d_in[3];
  const float* Wq_b = (const float*)d_in[4];
  const float* Wk_w = (const float*)d_in[5];
  const float* Wk_b = (const float*)d_in[6];
  const float* Wv_w = (const float*)d_in[7];
  const float* Wv_b = (const float*)d_in[8];
  const float* Wo_w = (const float*)d_in[9];
  const float* Wo_b = (const float*)d_in[10];
  const float* Wp_w = (const float*)d_in[11];
  const float* Wp_b = (const float*)d_in[12];

  char* ws = (char*)d_ws;
  u16* xq    = (u16*)(ws + 0);         // 8 MB  bf16 q_in
  u16* xk    = (u16*)(ws + 8388608);   // 8 MB
  u16* xv    = (u16*)(ws + 16777216);  // 8 MB
  u16* wq    = (u16*)(ws + 25165824);  // 512 KB each
  u16* wk    = (u16*)(ws + 25690112);
  u16* wv    = (u16*)(ws + 26214400);
  u16* wo    = (u16*)(ws + 26738688);
  u16* wp    = (u16*)(ws + 27262976);  // 4096x64 bf16 (row 4095 zero)
  u16* q_ws  = (u16*)(ws + 27787264);  // (b,h,l,d) bf16, pre-scaled log2e/8
  u16* k_ws  = (u16*)(ws + 36175872);
  u16* v_ws  = (u16*)(ws + 44564480);
  u16* opre  = (u16*)(ws + 52953088);  // (b*l, h*d) bf16 diag-scaled v
  float* psum  = (float*)(ws + 61341696);  // 1024 x 2 x 64 f32 partial sums
  float* pdiag = (float*)(ws + 61865984);  // 1024 x 64 f32 diagonal logits

  prep_kernel<<<6784, 256, 0, stream>>>(q_in, k_in, v_in, Wq_w, Wk_w, Wv_w, Wo_w, Wp_w,
                                        xq, xk, xv, wq, wk, wv, wo, wp);
  qkv_gemm<<<3072, 256, 0, stream>>>(xq, xk, xv, wq, wk, wv, Wq_b, Wk_b, Wv_b,
                                     q_ws, k_ws, v_ws);
  attn_kernel<<<2048, 256, 0, stream>>>(q_ws, k_ws, wp, Wp_b, psum, pdiag);
  combine_kernel<<<1024, 256, 0, stream>>>(v_ws, psum, pdiag, opre);
  gemm_bt<<<1024, 256, 0, stream>>>(opre, wo, Wo_b, (float*)d_out);
}

// Round 8
// 280.194 us; speedup vs baseline: 1.3730x; 1.0118x over previous
//
#include <hip/hip_runtime.h>
#include <cstdint>

// B=4, L=2048, H=512, HEADS=8, D=64.
// Only the DIAGONAL of softmax(scores) is consumed:
//   diag_i = exp(s_ii) / sum_j exp(s_ij),
//   s_ij = q_i.k_j + q_i.Wp[2047+j-i (padded)] + Wp_b[2047+j-i]
// Logits in log2 units (q pre-scaled by log2e/8 via prep-scaled Wq, bias by log2e).

typedef unsigned short u16;
typedef __bf16 bf16x8 __attribute__((ext_vector_type(8)));
typedef __bf16 bf16x2 __attribute__((ext_vector_type(2)));
typedef float  f32x16 __attribute__((ext_vector_type(16)));
typedef uint32_t __attribute__((address_space(1))) as1_u32;
typedef uint32_t __attribute__((address_space(3))) as3_u32;

__device__ __forceinline__ u16 f2bf(float f) {
  __bf16 h = (__bf16)f;
  return __builtin_bit_cast(u16, h);
}
__device__ __forceinline__ uint32_t pkbf(float a, float b) {
  bf16x2 v; v[0] = (__bf16)a; v[1] = (__bf16)b;
  return __builtin_bit_cast(uint32_t, v);
}
__device__ __forceinline__ float bf2f(u16 u) {
  return __uint_as_float(((uint32_t)u) << 16);
}
__device__ __forceinline__ float exp2v(float x) {
  float r;
  asm("v_exp_f32 %0, %1" : "=v"(r) : "v"(x));
  return r;
}
__device__ __forceinline__ void gl_lds16(const void* g, void* l) {
  __builtin_amdgcn_global_load_lds((const as1_u32*)g, (as3_u32*)l, 16, 0, 0);
}

// ---------------------------------------------------------------------------
// Prep: fp32 -> bf16 for q_in/k_in/v_in, Wq/Wk/Wv/Wo, Wp (padded to 4096 rows)
// Wq is pre-scaled by log2e/8 so the QKV epilogue needs no multiply.
// ---------------------------------------------------------------------------
__global__ __launch_bounds__(256) void prep_kernel(
    const float* __restrict__ qin, const float* __restrict__ kin, const float* __restrict__ vin,
    const float* __restrict__ wq,  const float* __restrict__ wk,  const float* __restrict__ wv,
    const float* __restrict__ wo,  const float* __restrict__ wp,
    u16* __restrict__ xq, u16* __restrict__ xk, u16* __restrict__ xv,
    u16* __restrict__ bwq, u16* __restrict__ bwk, u16* __restrict__ bwv,
    u16* __restrict__ bwo, u16* __restrict__ bwp) {
  long u = (long)blockIdx.x * 256 + threadIdx.x;
  const float* src; u16* dst; long off; float qs = 1.0f;
  if      (u < 524288L)  { src = qin; dst = xq;  off = u; }
  else if (u < 1048576L) { src = kin; dst = xk;  off = u - 524288L; }
  else if (u < 1572864L) { src = vin; dst = xv;  off = u - 1048576L; }
  else if (u < 1605632L) { src = wq;  dst = bwq; off = u - 1572864L; qs = 0.18033688f; }
  else if (u < 1638400L) { src = wk;  dst = bwk; off = u - 1605632L; }
  else if (u < 1671168L) { src = wv;  dst = bwv; off = u - 1638400L; }
  else if (u < 1703936L) { src = wo;  dst = bwo; off = u - 1671168L; }
  else if (u < 1736696L) { src = wp;  dst = bwp; off = u - 1703936L; }
  else {  // zero-fill Wp pad row 4095
    long o = (u - 1736696L) * 8 + 262080L;
    uint4 z = {0u, 0u, 0u, 0u};
    *(uint4*)(bwp + o) = z;
    return;
  }
  const float4* s4 = (const float4*)(src + off * 8);
  float4 a = s4[0], b = s4[1];
  uint32_t p0 = pkbf(a.x * qs, a.y * qs);
  uint32_t p1 = pkbf(a.z * qs, a.w * qs);
  uint32_t p2 = pkbf(b.x * qs, b.y * qs);
  uint32_t p3 = pkbf(b.z * qs, b.w * qs);
  uint4 o = {p0, p1, p2, p3};
  *(uint4*)(dst + off * 8) = o;
}

// ---------------------------------------------------------------------------
// 64x64-tile GEMM core (C = A @ W^T), 4 waves, each wave one 32x32 quadrant.
// ---------------------------------------------------------------------------
__device__ __forceinline__ void gemm64_core(
    const u16* __restrict__ A, const u16* __restrict__ W, int m0, int n0,
    u16* Al, u16* Bl, int tid, f32x16& acc) {
  const int lane = tid & 63, w = tid >> 6;
  const int wi = w >> 1, wj = w & 1;
  const int l31 = lane & 31, lh = lane >> 5;
  const int r = tid >> 2, ch = tid & 3;
  const int gch = ch ^ ((r >> 1) & 3);
  for (int kb = 0; kb < 16; ++kb) {
    gl_lds16(A + (long)(m0 + r) * 512 + kb * 32 + gch * 8, (char*)Al + w * 64 * 16);
    gl_lds16(W + (long)(n0 + r) * 512 + kb * 32 + gch * 8, (char*)Bl + w * 64 * 16);
    __syncthreads();
    bf16x8 af[2], bfr[2];
#pragma unroll
    for (int ks = 0; ks < 2; ++ks) {
      int c2 = 2 * ks + lh;
      int rA = 32 * wi + l31;
      int rB = 32 * wj + l31;
      af[ks]  = *(const bf16x8*)((char*)Al + (rA * 4 + (c2 ^ ((rA >> 1) & 3))) * 16);
      bfr[ks] = *(const bf16x8*)((char*)Bl + (rB * 4 + (c2 ^ ((rB >> 1) & 3))) * 16);
    }
#pragma unroll
    for (int ks = 0; ks < 2; ++ks)
      acc = __builtin_amdgcn_mfma_f32_32x32x16_bf16(af[ks], bfr[ks], acc, 0, 0, 0);
    __syncthreads();
  }
}

// gemm_bt: final projection, fp32 out row-major. 1024 blocks.
__global__ __launch_bounds__(256, 4) void gemm_bt(
    const u16* __restrict__ A, const u16* __restrict__ W, const float* __restrict__ bias,
    float* __restrict__ ofp) {
  __shared__ u16 Al[64 * 32];
  __shared__ u16 Bl[64 * 32];
  const int tid = threadIdx.x;
  const int lane = tid & 63, w = tid >> 6;
  const int wi = w >> 1, wj = w & 1;
  const int l31 = lane & 31, lh = lane >> 5;
  const int u = (blockIdx.x & 7) * 128 + (blockIdx.x >> 3);
  const int m0 = (u >> 3) * 64, n0 = (u & 7) * 64;

  float bv = bias[n0 + 32 * wj + l31];
  f32x16 acc;
#pragma unroll
  for (int rr = 0; rr < 16; ++rr) acc[rr] = bv;

  gemm64_core(A, W, m0, n0, Al, Bl, tid, acc);

  int n = n0 + 32 * wj + l31;
#pragma unroll
  for (int rr = 0; rr < 16; ++rr) {
    int row = m0 + 32 * wi + (rr & 3) + 8 * (rr >> 2) + 4 * lh;
    ofp[(long)row * 512 + n] = acc[rr];
  }
}

// qkv_gemm: 3072 blocks (3 mats x 1024), bf16 out in (b,h,l,d).
__global__ __launch_bounds__(256, 4) void qkv_gemm(
    const u16* __restrict__ xq, const u16* __restrict__ xk, const u16* __restrict__ xv,
    const u16* __restrict__ wqp, const u16* __restrict__ wkp, const u16* __restrict__ wvp,
    const float* __restrict__ bq, const float* __restrict__ bk, const float* __restrict__ bv,
    u16* __restrict__ oq, u16* __restrict__ ok, u16* __restrict__ ov) {
  __shared__ u16 Al[64 * 32];
  __shared__ u16 Bl[64 * 32];
  const int mat = blockIdx.x >> 10;
  const int t = blockIdx.x & 1023;
  const u16* A = (mat == 0) ? xq : (mat == 1) ? xk : xv;
  const u16* W = (mat == 0) ? wqp : (mat == 1) ? wkp : wvp;
  const float* bias = (mat == 0) ? bq : (mat == 1) ? bk : bv;
  u16* obf = (mat == 0) ? oq : (mat == 1) ? ok : ov;
  const float bsc = (mat == 0) ? 0.18033688f : 1.0f;

  const int tid = threadIdx.x;
  const int lane = tid & 63, w = tid >> 6;
  const int wi = w >> 1, wj = w & 1;
  const int l31 = lane & 31, lh = lane >> 5;
  const int u = (t & 7) * 128 + (t >> 3);
  const int m0 = (u >> 3) * 64, n0 = (u & 7) * 64;

  float bvv = bias[n0 + 32 * wj + l31] * bsc;
  f32x16 acc;
#pragma unroll
  for (int rr = 0; rr < 16; ++rr) acc[rr] = bvv;

  gemm64_core(A, W, m0, n0, Al, Bl, tid, acc);

  int n = n0 + 32 * wj + l31;
  int h = n >> 6, d = n & 63;
#pragma unroll
  for (int rr = 0; rr < 16; ++rr) {
    int row = m0 + 32 * wi + (rr & 3) + 8 * (rr >> 2) + 4 * lh;
    int b = row >> 11, l = row & 2047;
    obf[(((long)(b * 8 + h)) * 2048 + l) * 64 + d] = f2bf(acc[rr]);
  }
}

// ---------------------------------------------------------------------------
// Attention v8: wave-PRIVATE LDS P-buffer, zero barriers, minimal registers.
// 2048 blocks (b,h, 64-row i-tile, column half), 4 waves, (256,4).
// Each wave owns a 96x32 u16 LDS region (stride 34 u16, conflict-free:
// bank = 17*l31+2*lh+c mod 32, collisions only 2-way = free):
//   layout [trow][qrow]; rolling slots: tile t -> trow 32*(t&1)..+31;
//   even tiles ALSO mirrored at trow 64..95 so a step's 63-row read span
//   never wraps. Gather for score reg r = ONE ds_read_u16 at
//   base(t&1) - 33*lrr (compile-time immediate), no cndmask/bpermute.
// Step: kf loads -> 16 ds_read gather (accS C-init) -> 4 S-MFMA -> diag ->
//   bw loads (t+2) -> exp+rsum (accS dies) -> P-MFMA + pack + 8 ds_write
//   (+8 mirror every other tile). Carried regs: aq16+rsum16+consts (~40).
// Window math: W(j,r)=2047+j-r; wb=2016+c0-r0; trow idx=31+l31-lrr-4lh in
// [0,62]; max Wp row = 4095 (zero pad row), bias clamp 4094 (never read).
// ---------------------------------------------------------------------------
#define PTILE(G, S, DOMIR)                                                       \
  do {                                                                           \
    int wr_ = wb + 32 * (G) + l31;                                               \
    const u16* bp_ = wpw + (long)wr_ * 64 + lh * 8;                              \
    bf16x8 pw0 = *(const bf16x8*)(bp_);                                          \
    bf16x8 pw1 = *(const bf16x8*)(bp_ + 16);                                     \
    bf16x8 pw2 = *(const bf16x8*)(bp_ + 32);                                     \
    bf16x8 pw3 = *(const bf16x8*)(bp_ + 48);                                     \
    float pbv = wpb[wr_ > 4094 ? 4094 : wr_] * 1.44269504f;                      \
    f32x16 accP;                                                                 \
    _Pragma("unroll")                                                            \
    for (int r = 0; r < 16; ++r) accP[r] = pbv;                                  \
    accP = __builtin_amdgcn_mfma_f32_32x32x16_bf16(aq0, pw0, accP, 0, 0, 0);     \
    accP = __builtin_amdgcn_mfma_f32_32x32x16_bf16(aq1, pw1, accP, 0, 0, 0);     \
    accP = __builtin_amdgcn_mfma_f32_32x32x16_bf16(aq2, pw2, accP, 0, 0, 0);     \
    accP = __builtin_amdgcn_mfma_f32_32x32x16_bf16(aq3, pw3, accP, 0, 0, 0);     \
    uint32_t* b32 = (uint32_t*)(Plw + (32 * (S) + l31) * 34 + 4 * lh);           \
    uint32_t q0 = pkbf(accP[0], accP[1]),  q1 = pkbf(accP[2], accP[3]);          \
    uint32_t q2 = pkbf(accP[4], accP[5]),  q3 = pkbf(accP[6], accP[7]);          \
    uint32_t q4 = pkbf(accP[8], accP[9]),  q5 = pkbf(accP[10], accP[11]);        \
    uint32_t q6 = pkbf(accP[12], accP[13]), q7 = pkbf(accP[14], accP[15]);       \
    b32[0] = q0; b32[1] = q1; b32[4] = q2; b32[5] = q3;                          \
    b32[8] = q4; b32[9] = q5; b32[12] = q6; b32[13] = q7;                        \
    if (DOMIR) {                                                                 \
      b32[1088] = q0; b32[1089] = q1; b32[1092] = q2; b32[1093] = q3;            \
      b32[1096] = q4; b32[1097] = q5; b32[1100] = q6; b32[1101] = q7;            \
    }                                                                            \
  } while (0)

#define ATTN_STEP(T, DO_NEXT)                                                    \
  do {                                                                           \
    const int t_ = (T);                                                          \
    const u16* kp_ = kb + (long)(c0 + 32 * t_ + l31) * 64 + lh * 8;              \
    bf16x8 kf0 = *(const bf16x8*)(kp_);                                          \
    bf16x8 kf1 = *(const bf16x8*)(kp_ + 16);                                     \
    bf16x8 kf2 = *(const bf16x8*)(kp_ + 32);                                     \
    bf16x8 kf3 = *(const bf16x8*)(kp_ + 48);                                     \
    const u16* rb = ((T) & 1) ? rb1 : rb0;                                       \
    f32x16 accS;                                                                 \
    _Pragma("unroll")                                                            \
    for (int r = 0; r < 16; ++r) {                                               \
      const int lrr = (r & 3) + 8 * (r >> 2);                                    \
      accS[r] = __uint_as_float(((uint32_t)rb[33 * (27 - lrr)]) << 16);          \
    }                                                                            \
    accS = __builtin_amdgcn_mfma_f32_32x32x16_bf16(aq0, kf0, accS, 0, 0, 0);     \
    accS = __builtin_amdgcn_mfma_f32_32x32x16_bf16(aq1, kf1, accS, 0, 0, 0);     \
    accS = __builtin_amdgcn_mfma_f32_32x32x16_bf16(aq2, kf2, accS, 0, 0, 0);     \
    accS = __builtin_amdgcn_mfma_f32_32x32x16_bf16(aq3, kf3, accS, 0, 0, 0);     \
    if (t_ == td) {                                                              \
      _Pragma("unroll")                                                          \
      for (int r = 0; r < 16; ++r) {                                             \
        const int lrr = (r & 3) + 8 * (r >> 2);                                  \
        if (l31 == lrr + 4 * lh) pdiag[tb64 + 32 * wi + l31] = accS[r];          \
      }                                                                          \
    }                                                                            \
    _Pragma("unroll")                                                            \
    for (int r = 0; r < 16; ++r) rsum[r] += exp2v(accS[r]);                      \
    if (DO_NEXT) { PTILE(t_ + 2, (t_ & 1), ((t_ & 1) == 0)); }                   \
  } while (0)

__global__ __launch_bounds__(256, 4) void attn_kernel(
    const u16* __restrict__ qw, const u16* __restrict__ kw,
    const u16* __restrict__ wpw, const float* __restrict__ wpb,
    float* __restrict__ psum, float* __restrict__ pdiag) {
  __shared__ u16 Pl[4 * 96 * 34];     // 26112 B: 4 wave-private 96x34 regions
  __shared__ float rssum[128];

  const int tid = threadIdx.x, lane = tid & 63, w = tid >> 6;
  const int wi = w >> 1, wj = w & 1;
  // XCD swizzle: 2048 blocks; XCD x gets bh in {x, x+8, x+16, x+24}.
  const int sbi = blockIdx.x;
  const int x = sbi & 7, g = sbi >> 3;          // g in 0..255
  const int bh = x + 8 * (g >> 6);
  const int rem = g & 63;
  const int it = rem >> 1, half = rem & 1;
  const int i0 = it * 64;
  const u16* qb = qw + (long)bh * 2048 * 64;
  const u16* kb = kw + (long)bh * 2048 * 64;

  const int l31 = lane & 31, lh = lane >> 5;
  const int r0 = i0 + 32 * wi;
  const int c0 = 1024 * half + 512 * wj;
  const int wb = 2016 + c0 - r0;               // window base at t=0
  const long tb64 = (long)(bh * 32 + it) * 64;

  u16* Plw = Pl + w * 3264;                    // 96*34 per wave
  // gather read bases (u16 index): byte = 68*trow + 2*qrow,
  // trow = 32*sA + 31 + l31 - 4lh - lrr, qrow = lrr + 4lh
  // => idx_u16 = 34*(32*sA + 31 + l31 - 4lh) + 4lh - 33*lrr; fold -33*27.
  const u16* rb0 = Plw + 34 * (31 + l31 - 4 * lh) + 4 * lh - 891;
  const u16* rb1 = rb0 + 1088;

  // A-fragments: Q rows r0 + l31, full K=64 (log2e/8 pre-scaled)
  bf16x8 aq0, aq1, aq2, aq3;
  {
    const u16* p = qb + (long)(r0 + l31) * 64 + lh * 8;
    aq0 = *(const bf16x8*)(p);
    aq1 = *(const bf16x8*)(p + 16);
    aq2 = *(const bf16x8*)(p + 32);
    aq3 = *(const bf16x8*)(p + 48);
  }

  float rsum[16];
#pragma unroll
  for (int r = 0; r < 16; ++r) rsum[r] = 0.f;

  int td = -1;  // step holding this wave's diagonal (if any)
  {
    int tdn = r0 - c0;
    if (tdn >= 0 && tdn < 512) td = tdn >> 5;
  }

  // prologue: tiles 0 (slot 0 + mirror) and 1 (slot 1)
  PTILE(0, 0, true);
  PTILE(1, 1, false);

  // main loop: 16 steps, 2-unrolled (rb0/rb1 + slot parity static).
  for (int tt = 0; tt < 14; tt += 2) {
    ATTN_STEP(tt, true);
    ATTN_STEP(tt + 1, true);
  }
  ATTN_STEP(14, true);
  ATTN_STEP(15, false);

  // reduce row partials across the 32 lanes sharing each row
#pragma unroll
  for (int r = 0; r < 16; ++r) {
    float v = rsum[r];
    v += __shfl_xor(v, 1);
    v += __shfl_xor(v, 2);
    v += __shfl_xor(v, 4);
    v += __shfl_xor(v, 8);
    v += __shfl_xor(v, 16);
    rsum[r] = v;
  }
  if (l31 == 0) {
#pragma unroll
    for (int r = 0; r < 16; ++r) {
      int lr = (r & 3) + 8 * (r >> 2) + 4 * lh;
      rssum[(32 * wi + lr) * 2 + wj] = rsum[r];
    }
  }
  __syncthreads();
  if (tid < 64) {
    float S = rssum[2 * tid] + rssum[2 * tid + 1];
    psum[(tb64 * 2) + half * 64 + tid] = S;   // ((bh*32+it)*2 + half)*64 + row
  }
}

// ---------------------------------------------------------------------------
// Combine: attw = exp2(diag) / (psum_half0 + psum_half1); out_pre = attw * v.
// 1024 blocks x 256 threads; each block one (bh, 64-row i-tile).
// ---------------------------------------------------------------------------
__global__ __launch_bounds__(256) void combine_kernel(
    const u16* __restrict__ vw, const float* __restrict__ psum,
    const float* __restrict__ pdiag, u16* __restrict__ outp) {
  const int u = blockIdx.x;            // bh*32 + it
  const int bh = u >> 5, it = u & 31, i0 = it * 64;
  const int tid = threadIdx.x;
  const int r = tid >> 2, dd = (tid & 3) * 16;
  float S = psum[u * 128 + r] + psum[u * 128 + 64 + r];
  float a = exp2v(pdiag[u * 64 + r]) / S;
  const int b = bh >> 3, h = bh & 7;
  const u16* vp = vw + (long)bh * 2048 * 64 + (long)(i0 + r) * 64 + dd;
  u16* op = outp + ((long)(b * 2048 + i0 + r)) * 512 + h * 64 + dd;
  uint4 v0 = *(const uint4*)vp;
  uint4 v1 = *(const uint4*)(vp + 8);
  uint32_t vin[8] = {v0.x, v0.y, v0.z, v0.w, v1.x, v1.y, v1.z, v1.w};
  uint32_t vout[8];
#pragma unroll
  for (int e = 0; e < 8; ++e) {
    float lo = bf2f((u16)(vin[e] & 0xffffu)) * a;
    float hi = bf2f((u16)(vin[e] >> 16)) * a;
    vout[e] = pkbf(lo, hi);
  }
  uint4 o0 = {vout[0], vout[1], vout[2], vout[3]};
  uint4 o1 = {vout[4], vout[5], vout[6], vout[7]};
  *(uint4*)op = o0;
  *(uint4*)(op + 8) = o1;
}

// ---------------------------------------------------------------------------
extern "C" void kernel_launch(void* const* d_in, const int* in_sizes, int n_in,
                              void* d_out, int out_size, void* d_ws, size_t ws_size,
                              hipStream_t stream) {
  (void)in_sizes; (void)n_in; (void)out_size; (void)ws_size;
  const float* q_in = (const float*)d_in[0];
  const float* k_in = (const float*)d_in[1];
  const float* v_in = (const float*)d_in[2];
  const float* Wq_w = (const float*)d_in[3];
  const float* Wq_b = (const float*)d_in[4];
  const float* Wk_w = (const float*)d_in[5];
  const float* Wk_b = (const float*)d_in[6];
  const float* Wv_w = (const float*)d_in[7];
  const float* Wv_b = (const float*)d_in[8];
  const float* Wo_w = (const float*)d_in[9];
  const float* Wo_b = (const float*)d_in[10];
  const float* Wp_w = (const float*)d_in[11];
  const float* Wp_b = (const float*)d_in[12];

  char* ws = (char*)d_ws;
  u16* xq    = (u16*)(ws + 0);         // 8 MB  bf16 q_in
  u16* xk    = (u16*)(ws + 8388608);   // 8 MB
  u16* xv    = (u16*)(ws + 16777216);  // 8 MB
  u16* wq    = (u16*)(ws + 25165824);  // 512 KB each
  u16* wk    = (u16*)(ws + 25690112);
  u16* wv    = (u16*)(ws + 26214400);
  u16* wo    = (u16*)(ws + 26738688);
  u16* wp    = (u16*)(ws + 27262976);  // 4096x64 bf16 (row 4095 zero)
  u16* q_ws  = (u16*)(ws + 27787264);  // (b,h,l,d) bf16, pre-scaled log2e/8
  u16* k_ws  = (u16*)(ws + 36175872);
  u16* v_ws  = (u16*)(ws + 44564480);
  u16* opre  = (u16*)(ws + 52953088);  // (b*l, h*d) bf16 diag-scaled v
  float* psum  = (float*)(ws + 61341696);  // 1024 x 2 x 64 f32 partial sums
  float* pdiag = (float*)(ws + 61865984);  // 1024 x 64 f32 diagonal logits

  prep_kernel<<<6784, 256, 0, stream>>>(q_in, k_in, v_in, Wq_w, Wk_w, Wv_w, Wo_w, Wp_w,
                                        xq, xk, xv, wq, wk, wv, wo, wp);
  qkv_gemm<<<3072, 256, 0, stream>>>(xq, xk, xv, wq, wk, wv, Wq_b, Wk_b, Wv_b,
                                     q_ws, k_ws, v_ws);
  attn_kernel<<<2048, 256, 0, stream>>>(q_ws, k_ws, wp, Wp_b, psum, pdiag);
  combine_kernel<<<1024, 256, 0, stream>>>(v_ws, psum, pdiag, opre);
  gemm_bt<<<1024, 256, 0, stream>>>(opre, wo, Wo_b, (float*)d_out);
}

// Round 9
// 224.208 us; speedup vs baseline: 1.7158x; 1.2497x over previous
//
#include <hip/hip_runtime.h>
#include <cstdint>

// B=4, L=2048, H=512, HEADS=8, D=64.
// Only the DIAGONAL of softmax(scores) is consumed:
//   diag_i = exp(s_ii) / sum_j exp(s_ij),
//   s_ij = q_i.k_j + q_i.Wp[2047+j-i (padded)] + Wp_b[2047+j-i]
// Logits in log2 units (q pre-scaled by log2e/8 via prep-scaled Wq, bias by log2e).

typedef unsigned short u16;
typedef __bf16 bf16x8 __attribute__((ext_vector_type(8)));
typedef __bf16 bf16x2 __attribute__((ext_vector_type(2)));
typedef float  f32x16 __attribute__((ext_vector_type(16)));
typedef uint32_t __attribute__((address_space(1))) as1_u32;
typedef uint32_t __attribute__((address_space(3))) as3_u32;

__device__ __forceinline__ u16 f2bf(float f) {
  __bf16 h = (__bf16)f;
  return __builtin_bit_cast(u16, h);
}
__device__ __forceinline__ uint32_t pkbf(float a, float b) {
  bf16x2 v; v[0] = (__bf16)a; v[1] = (__bf16)b;
  return __builtin_bit_cast(uint32_t, v);
}
__device__ __forceinline__ float bf2f(u16 u) {
  return __uint_as_float(((uint32_t)u) << 16);
}
__device__ __forceinline__ float exp2v(float x) {
  float r;
  asm("v_exp_f32 %0, %1" : "=v"(r) : "v"(x));
  return r;
}
__device__ __forceinline__ void gl_lds16(const void* g, void* l) {
  __builtin_amdgcn_global_load_lds((const as1_u32*)g, (as3_u32*)l, 16, 0, 0);
}

// ---------------------------------------------------------------------------
// Prep: fp32 -> bf16 for q_in/k_in/v_in, Wq/Wk/Wv/Wo, Wp (padded to 4096 rows)
// Wq is pre-scaled by log2e/8 so the QKV epilogue needs no multiply.
// ---------------------------------------------------------------------------
__global__ __launch_bounds__(256) void prep_kernel(
    const float* __restrict__ qin, const float* __restrict__ kin, const float* __restrict__ vin,
    const float* __restrict__ wq,  const float* __restrict__ wk,  const float* __restrict__ wv,
    const float* __restrict__ wo,  const float* __restrict__ wp,
    u16* __restrict__ xq, u16* __restrict__ xk, u16* __restrict__ xv,
    u16* __restrict__ bwq, u16* __restrict__ bwk, u16* __restrict__ bwv,
    u16* __restrict__ bwo, u16* __restrict__ bwp) {
  long u = (long)blockIdx.x * 256 + threadIdx.x;
  const float* src; u16* dst; long off; float qs = 1.0f;
  if      (u < 524288L)  { src = qin; dst = xq;  off = u; }
  else if (u < 1048576L) { src = kin; dst = xk;  off = u - 524288L; }
  else if (u < 1572864L) { src = vin; dst = xv;  off = u - 1048576L; }
  else if (u < 1605632L) { src = wq;  dst = bwq; off = u - 1572864L; qs = 0.18033688f; }
  else if (u < 1638400L) { src = wk;  dst = bwk; off = u - 1605632L; }
  else if (u < 1671168L) { src = wv;  dst = bwv; off = u - 1638400L; }
  else if (u < 1703936L) { src = wo;  dst = bwo; off = u - 1671168L; }
  else if (u < 1736696L) { src = wp;  dst = bwp; off = u - 1703936L; }
  else {  // zero-fill Wp pad row 4095
    long o = (u - 1736696L) * 8 + 262080L;
    uint4 z = {0u, 0u, 0u, 0u};
    *(uint4*)(bwp + o) = z;
    return;
  }
  const float4* s4 = (const float4*)(src + off * 8);
  float4 a = s4[0], b = s4[1];
  uint32_t p0 = pkbf(a.x * qs, a.y * qs);
  uint32_t p1 = pkbf(a.z * qs, a.w * qs);
  uint32_t p2 = pkbf(b.x * qs, b.y * qs);
  uint32_t p3 = pkbf(b.z * qs, b.w * qs);
  uint4 o = {p0, p1, p2, p3};
  *(uint4*)(dst + off * 8) = o;
}

// ---------------------------------------------------------------------------
// 64x64-tile GEMM core (C = A @ W^T), 4 waves, each wave one 32x32 quadrant.
// ---------------------------------------------------------------------------
__device__ __forceinline__ void gemm64_core(
    const u16* __restrict__ A, const u16* __restrict__ W, int m0, int n0,
    u16* Al, u16* Bl, int tid, f32x16& acc) {
  const int lane = tid & 63, w = tid >> 6;
  const int wi = w >> 1, wj = w & 1;
  const int l31 = lane & 31, lh = lane >> 5;
  const int r = tid >> 2, ch = tid & 3;
  const int gch = ch ^ ((r >> 1) & 3);
  for (int kb = 0; kb < 16; ++kb) {
    gl_lds16(A + (long)(m0 + r) * 512 + kb * 32 + gch * 8, (char*)Al + w * 64 * 16);
    gl_lds16(W + (long)(n0 + r) * 512 + kb * 32 + gch * 8, (char*)Bl + w * 64 * 16);
    __syncthreads();
    bf16x8 af[2], bfr[2];
#pragma unroll
    for (int ks = 0; ks < 2; ++ks) {
      int c2 = 2 * ks + lh;
      int rA = 32 * wi + l31;
      int rB = 32 * wj + l31;
      af[ks]  = *(const bf16x8*)((char*)Al + (rA * 4 + (c2 ^ ((rA >> 1) & 3))) * 16);
      bfr[ks] = *(const bf16x8*)((char*)Bl + (rB * 4 + (c2 ^ ((rB >> 1) & 3))) * 16);
    }
#pragma unroll
    for (int ks = 0; ks < 2; ++ks)
      acc = __builtin_amdgcn_mfma_f32_32x32x16_bf16(af[ks], bfr[ks], acc, 0, 0, 0);
    __syncthreads();
  }
}

// gemm_bt: final projection, fp32 out row-major. 1024 blocks.
__global__ __launch_bounds__(256, 4) void gemm_bt(
    const u16* __restrict__ A, const u16* __restrict__ W, const float* __restrict__ bias,
    float* __restrict__ ofp) {
  __shared__ u16 Al[64 * 32];
  __shared__ u16 Bl[64 * 32];
  const int tid = threadIdx.x;
  const int lane = tid & 63, w = tid >> 6;
  const int wi = w >> 1, wj = w & 1;
  const int l31 = lane & 31, lh = lane >> 5;
  const int u = (blockIdx.x & 7) * 128 + (blockIdx.x >> 3);
  const int m0 = (u >> 3) * 64, n0 = (u & 7) * 64;

  float bv = bias[n0 + 32 * wj + l31];
  f32x16 acc;
#pragma unroll
  for (int rr = 0; rr < 16; ++rr) acc[rr] = bv;

  gemm64_core(A, W, m0, n0, Al, Bl, tid, acc);

  int n = n0 + 32 * wj + l31;
#pragma unroll
  for (int rr = 0; rr < 16; ++rr) {
    int row = m0 + 32 * wi + (rr & 3) + 8 * (rr >> 2) + 4 * lh;
    ofp[(long)row * 512 + n] = acc[rr];
  }
}

// qkv_gemm: 3072 blocks (3 mats x 1024), bf16 out in (b,h,l,d).
__global__ __launch_bounds__(256, 4) void qkv_gemm(
    const u16* __restrict__ xq, const u16* __restrict__ xk, const u16* __restrict__ xv,
    const u16* __restrict__ wqp, const u16* __restrict__ wkp, const u16* __restrict__ wvp,
    const float* __restrict__ bq, const float* __restrict__ bk, const float* __restrict__ bv,
    u16* __restrict__ oq, u16* __restrict__ ok, u16* __restrict__ ov) {
  __shared__ u16 Al[64 * 32];
  __shared__ u16 Bl[64 * 32];
  const int mat = blockIdx.x >> 10;
  const int t = blockIdx.x & 1023;
  const u16* A = (mat == 0) ? xq : (mat == 1) ? xk : xv;
  const u16* W = (mat == 0) ? wqp : (mat == 1) ? wkp : wvp;
  const float* bias = (mat == 0) ? bq : (mat == 1) ? bk : bv;
  u16* obf = (mat == 0) ? oq : (mat == 1) ? ok : ov;
  const float bsc = (mat == 0) ? 0.18033688f : 1.0f;

  const int tid = threadIdx.x;
  const int lane = tid & 63, w = tid >> 6;
  const int wi = w >> 1, wj = w & 1;
  const int l31 = lane & 31, lh = lane >> 5;
  const int u = (t & 7) * 128 + (t >> 3);
  const int m0 = (u >> 3) * 64, n0 = (u & 7) * 64;

  float bvv = bias[n0 + 32 * wj + l31] * bsc;
  f32x16 acc;
#pragma unroll
  for (int rr = 0; rr < 16; ++rr) acc[rr] = bvv;

  gemm64_core(A, W, m0, n0, Al, Bl, tid, acc);

  int n = n0 + 32 * wj + l31;
  int h = n >> 6, d = n & 63;
#pragma unroll
  for (int rr = 0; rr < 16; ++rr) {
    int row = m0 + 32 * wi + (rr & 3) + 8 * (rr >> 2) + 4 * lh;
    int b = row >> 11, l = row & 2047;
    obf[(((long)(b * 8 + h)) * 2048 + l) * 64 + d] = f2bf(acc[rr]);
  }
}

// ---------------------------------------------------------------------------
// Attention v9: 64 q-rows per wave (2 row-sets A/B), barrier-free main loop,
// skewed wave-private LDS P-rings, K-frag reuse (A+B share), Wp-frag carry
// (B's tile t+2 = A's tile t+1, carried one step in regs). 1024 blocks:
// (b,h, 64-row i-tile); wave w=0..3 owns cols [512w, 512w+512), 16 steps.
// Skewed ring: cell (qrow q, window-row trow) stored at [u = (trow+q)&127]
// [v = q], row stride 36 u16 (72 B). Gather at step t: lane reads ONE row
// u = (31+l31+32t)&127 as 4x ds_read_b64 (runs v = 4lh+8k..+3), unpack via
// shift/mask (1 VALU each). Tile G writes u in [32G, 32G+62] - cell-disjoint
// with concurrent reads (period-4 mod-128 check verified). Per-step:
// 4 K loads -> gatherA -> 4 MFMA -> exp x16 -> gatherB -> 4 MFMA (K reused)
// -> exp x16 -> 4 Wp loads -> P_B (carried frags) -> P_A (new frags) -> carry.
// Diag: wave w==it>>3 at steps 2(it&7) (A-rows), +1 (B-rows) -> sdiag LDS.
// Block-local combine + V-scale epilogue (combine kernel eliminated).
// LDS 75.3 KB -> 2 blocks/CU; (256,2) gives 256-reg budget: no spill risk.
// Wp row max = wbA+32*16+31 = 4095 exactly (step 15 skips P phase); pad row
// 4095 is zeroed; bias clamp 4094 (cell w=4095 never gathered).
// ---------------------------------------------------------------------------
#define PCOMP(RING, G, AQ0, AQ1, AQ2, AQ3, B0, B1, B2, B3, BV)                   \
  do {                                                                           \
    f32x16 accP;                                                                 \
    _Pragma("unroll")                                                            \
    for (int r = 0; r < 16; ++r) accP[r] = (BV);                                 \
    accP = __builtin_amdgcn_mfma_f32_32x32x16_bf16(AQ0, B0, accP, 0, 0, 0);      \
    accP = __builtin_amdgcn_mfma_f32_32x32x16_bf16(AQ1, B1, accP, 0, 0, 0);      \
    accP = __builtin_amdgcn_mfma_f32_32x32x16_bf16(AQ2, B2, accP, 0, 0, 0);      \
    accP = __builtin_amdgcn_mfma_f32_32x32x16_bf16(AQ3, B3, accP, 0, 0, 0);      \
    int bw_ = 32 * (G) + l31 + 4 * lh;                                           \
    _Pragma("unroll")                                                            \
    for (int r = 0; r < 16; ++r) {                                               \
      const int lrr = (r & 3) + 8 * (r >> 2);                                    \
      int uu = (bw_ + lrr) & 127;                                                \
      (RING)[uu * 36 + lrr + 4 * lh] = f2bf(accP[r]);                            \
    }                                                                            \
  } while (0)

#define GATH(RING, T, ACC)                                                       \
  do {                                                                           \
    int u_ = (31 + l31 + 32 * (T)) & 127;                                        \
    const u16* p_ = (RING) + u_ * 36 + 4 * lh;                                   \
    uint2 g0 = *(const uint2*)(p_);                                              \
    uint2 g1 = *(const uint2*)(p_ + 8);                                          \
    uint2 g2 = *(const uint2*)(p_ + 16);                                         \
    uint2 g3 = *(const uint2*)(p_ + 24);                                         \
    ACC[0]  = __uint_as_float(g0.x << 16); ACC[1]  = __uint_as_float(g0.x & 0xffff0000u); \
    ACC[2]  = __uint_as_float(g0.y << 16); ACC[3]  = __uint_as_float(g0.y & 0xffff0000u); \
    ACC[4]  = __uint_as_float(g1.x << 16); ACC[5]  = __uint_as_float(g1.x & 0xffff0000u); \
    ACC[6]  = __uint_as_float(g1.y << 16); ACC[7]  = __uint_as_float(g1.y & 0xffff0000u); \
    ACC[8]  = __uint_as_float(g2.x << 16); ACC[9]  = __uint_as_float(g2.x & 0xffff0000u); \
    ACC[10] = __uint_as_float(g2.y << 16); ACC[11] = __uint_as_float(g2.y & 0xffff0000u); \
    ACC[12] = __uint_as_float(g3.x << 16); ACC[13] = __uint_as_float(g3.x & 0xffff0000u); \
    ACC[14] = __uint_as_float(g3.y << 16); ACC[15] = __uint_as_float(g3.y & 0xffff0000u); \
  } while (0)

#define ATTN_STEP(T, DO_P)                                                       \
  do {                                                                           \
    const int t_ = (T);                                                          \
    const u16* kp_ = kb + (long)(c0 + 32 * t_ + l31) * 64 + lh * 8;              \
    bf16x8 kf0 = *(const bf16x8*)(kp_);                                          \
    bf16x8 kf1 = *(const bf16x8*)(kp_ + 16);                                     \
    bf16x8 kf2 = *(const bf16x8*)(kp_ + 32);                                     \
    bf16x8 kf3 = *(const bf16x8*)(kp_ + 48);                                     \
    {                                                                            \
      f32x16 accS;                                                               \
      GATH(ringA, t_, accS);                                                     \
      accS = __builtin_amdgcn_mfma_f32_32x32x16_bf16(aqA0, kf0, accS, 0, 0, 0);  \
      accS = __builtin_amdgcn_mfma_f32_32x32x16_bf16(aqA1, kf1, accS, 0, 0, 0);  \
      accS = __builtin_amdgcn_mfma_f32_32x32x16_bf16(aqA2, kf2, accS, 0, 0, 0);  \
      accS = __builtin_amdgcn_mfma_f32_32x32x16_bf16(aqA3, kf3, accS, 0, 0, 0);  \
      if (diagw && t_ == tdA) {                                                  \
        _Pragma("unroll")                                                        \
        for (int r = 0; r < 16; ++r) {                                           \
          const int lrr = (r & 3) + 8 * (r >> 2);                                \
          if (l31 == lrr + 4 * lh) sdiag[lrr + 4 * lh] = accS[r];                \
        }                                                                        \
      }                                                                          \
      _Pragma("unroll")                                                          \
      for (int r = 0; r < 16; ++r) rsum[r] += exp2v(accS[r]);                    \
    }                                                                            \
    {                                                                            \
      f32x16 accS;                                                               \
      GATH(ringB, t_, accS);                                                     \
      accS = __builtin_amdgcn_mfma_f32_32x32x16_bf16(aqB0, kf0, accS, 0, 0, 0);  \
      accS = __builtin_amdgcn_mfma_f32_32x32x16_bf16(aqB1, kf1, accS, 0, 0, 0);  \
      accS = __builtin_amdgcn_mfma_f32_32x32x16_bf16(aqB2, kf2, accS, 0, 0, 0);  \
      accS = __builtin_amdgcn_mfma_f32_32x32x16_bf16(aqB3, kf3, accS, 0, 0, 0);  \
      if (diagw && t_ == tdA + 1) {                                              \
        _Pragma("unroll")                                                        \
        for (int r = 0; r < 16; ++r) {                                           \
          const int lrr = (r & 3) + 8 * (r >> 2);                                \
          if (l31 == lrr + 4 * lh) sdiag[32 + lrr + 4 * lh] = accS[r];           \
        }                                                                        \
      }                                                                          \
      _Pragma("unroll")                                                          \
      for (int r = 0; r < 16; ++r) rsum[16 + r] += exp2v(accS[r]);               \
    }                                                                            \
    if (DO_P) {                                                                  \
      int wr_ = wbA + 32 * (t_ + 2) + l31;                                       \
      const u16* bp_ = wpw + (long)wr_ * 64 + lh * 8;                            \
      bf16x8 nb0 = *(const bf16x8*)(bp_);                                        \
      bf16x8 nb1 = *(const bf16x8*)(bp_ + 16);                                   \
      bf16x8 nb2 = *(const bf16x8*)(bp_ + 32);                                   \
      bf16x8 nb3 = *(const bf16x8*)(bp_ + 48);                                   \
      float nbv = wpb[wr_ > 4094 ? 4094 : wr_] * 1.44269504f;                    \
      PCOMP(ringB, t_ + 2, aqB0, aqB1, aqB2, aqB3, cb0, cb1, cb2, cb3, cbv);     \
      PCOMP(ringA, t_ + 2, aqA0, aqA1, aqA2, aqA3, nb0, nb1, nb2, nb3, nbv);     \
      cb0 = nb0; cb1 = nb1; cb2 = nb2; cb3 = nb3; cbv = nbv;                     \
    }                                                                            \
  } while (0)

__global__ __launch_bounds__(256, 2) void attn_kernel(
    const u16* __restrict__ qw, const u16* __restrict__ kw, const u16* __restrict__ vw,
    const u16* __restrict__ wpw, const float* __restrict__ wpb, u16* __restrict__ outp) {
  __shared__ u16 Pl[8 * 128 * 36];   // 73728 B: per wave 2 skewed rings (A,B)
  __shared__ float sdiag[64];
  __shared__ float rssum[64 * 4];
  __shared__ float attw[64];

  const int tid = threadIdx.x, lane = tid & 63, w = tid >> 6;
  // XCD swizzle: 1024 blocks; XCD x gets bh in {x, x+8, x+16, x+24}.
  const int sbi = blockIdx.x;
  const int x = sbi & 7, g = sbi >> 3;          // g in 0..127
  const int bh = x + 8 * (g >> 5);
  const int it = g & 31;
  const int i0 = it * 64;
  const u16* qb = qw + (long)bh * 2048 * 64;
  const u16* kb = kw + (long)bh * 2048 * 64;
  const u16* vb = vw + (long)bh * 2048 * 64;

  const int l31 = lane & 31, lh = lane >> 5;
  const int c0 = w << 9;                        // wave's column base
  const int wbA = 2016 + c0 - i0;               // A window base (B = A - 32)
  const bool diagw = (w == (it >> 3));
  const int tdA = 2 * (it & 7);

  u16* ringA = Pl + w * 9216;                   // 128*36 u16 each
  u16* ringB = ringA + 4608;

  // A-fragments: q rows i0+l31 (set A) and i0+32+l31 (set B), full K=64
  bf16x8 aqA0, aqA1, aqA2, aqA3, aqB0, aqB1, aqB2, aqB3;
  {
    const u16* pA = qb + (long)(i0 + l31) * 64 + lh * 8;
    aqA0 = *(const bf16x8*)(pA);
    aqA1 = *(const bf16x8*)(pA + 16);
    aqA2 = *(const bf16x8*)(pA + 32);
    aqA3 = *(const bf16x8*)(pA + 48);
    const u16* pB = pA + 32 * 64;
    aqB0 = *(const bf16x8*)(pB);
    aqB1 = *(const bf16x8*)(pB + 16);
    aqB2 = *(const bf16x8*)(pB + 32);
    aqB3 = *(const bf16x8*)(pB + 48);
  }

  float rsum[32];
#pragma unroll
  for (int r = 0; r < 32; ++r) rsum[r] = 0.f;

  // carried Wp fragments (row-block m = t+1 during step t)
  bf16x8 cb0, cb1, cb2, cb3;
  float cbv;

  // prologue: Wp row-blocks m = -1 (B tile 0), 0 (A0 + B1), 1 (A1, carried)
  {
    int wr = wbA - 32 + l31;
    const u16* bp = wpw + (long)wr * 64 + lh * 8;
    bf16x8 f0 = *(const bf16x8*)(bp), f1 = *(const bf16x8*)(bp + 16);
    bf16x8 f2 = *(const bf16x8*)(bp + 32), f3 = *(const bf16x8*)(bp + 48);
    float fv = wpb[wr > 4094 ? 4094 : wr] * 1.44269504f;
    PCOMP(ringB, 0, aqB0, aqB1, aqB2, aqB3, f0, f1, f2, f3, fv);
  }
  {
    int wr = wbA + l31;
    const u16* bp = wpw + (long)wr * 64 + lh * 8;
    bf16x8 f0 = *(const bf16x8*)(bp), f1 = *(const bf16x8*)(bp + 16);
    bf16x8 f2 = *(const bf16x8*)(bp + 32), f3 = *(const bf16x8*)(bp + 48);
    float fv = wpb[wr > 4094 ? 4094 : wr] * 1.44269504f;
    PCOMP(ringA, 0, aqA0, aqA1, aqA2, aqA3, f0, f1, f2, f3, fv);
    PCOMP(ringB, 1, aqB0, aqB1, aqB2, aqB3, f0, f1, f2, f3, fv);
  }
  {
    int wr = wbA + 32 + l31;
    const u16* bp = wpw + (long)wr * 64 + lh * 8;
    cb0 = *(const bf16x8*)(bp); cb1 = *(const bf16x8*)(bp + 16);
    cb2 = *(const bf16x8*)(bp + 32); cb3 = *(const bf16x8*)(bp + 48);
    cbv = wpb[wr > 4094 ? 4094 : wr] * 1.44269504f;
    PCOMP(ringA, 1, aqA0, aqA1, aqA2, aqA3, cb0, cb1, cb2, cb3, cbv);
  }

  // main loop: 16 steps of 32 cols; step t gathers tiles t,t+1 and builds t+2.
  for (int t = 0; t < 15; ++t) {
    ATTN_STEP(t, true);
  }
  ATTN_STEP(15, false);

  // reduce row partials across the 32 col-lanes
#pragma unroll
  for (int r = 0; r < 32; ++r) {
    float v = rsum[r];
    v += __shfl_xor(v, 1);
    v += __shfl_xor(v, 2);
    v += __shfl_xor(v, 4);
    v += __shfl_xor(v, 8);
    v += __shfl_xor(v, 16);
    rsum[r] = v;
  }
  if (l31 == 0) {
#pragma unroll
    for (int r = 0; r < 16; ++r) {
      int lr = (r & 3) + 8 * (r >> 2) + 4 * lh;
      rssum[lr * 4 + w] = rsum[r];
      rssum[(32 + lr) * 4 + w] = rsum[16 + r];
    }
  }
  __syncthreads();
  if (tid < 64) {
    float S = rssum[tid * 4] + rssum[tid * 4 + 1] + rssum[tid * 4 + 2] + rssum[tid * 4 + 3];
    attw[tid] = exp2v(sdiag[tid]) / S;
  }
  __syncthreads();
  // out_pre[b*2048 + i][h*64 + d] = diag * v   (bf16)
  {
    int r = tid >> 2, dd = (tid & 3) * 16;
    float a = attw[r];
    int b = bh >> 3, h = bh & 7;
    const u16* vp = vb + (long)(i0 + r) * 64 + dd;
    u16* op = outp + ((long)(b * 2048 + i0 + r)) * 512 + h * 64 + dd;
    uint4 v0 = *(const uint4*)vp;
    uint4 v1 = *(const uint4*)(vp + 8);
    uint32_t vin[8] = {v0.x, v0.y, v0.z, v0.w, v1.x, v1.y, v1.z, v1.w};
    uint32_t vout[8];
#pragma unroll
    for (int e = 0; e < 8; ++e) {
      float lo = bf2f((u16)(vin[e] & 0xffffu)) * a;
      float hi = bf2f((u16)(vin[e] >> 16)) * a;
      vout[e] = pkbf(lo, hi);
    }
    uint4 o0 = {vout[0], vout[1], vout[2], vout[3]};
    uint4 o1 = {vout[4], vout[5], vout[6], vout[7]};
    *(uint4*)op = o0;
    *(uint4*)(op + 8) = o1;
  }
}

// ---------------------------------------------------------------------------
extern "C" void kernel_launch(void* const* d_in, const int* in_sizes, int n_in,
                              void* d_out, int out_size, void* d_ws, size_t ws_size,
                              hipStream_t stream) {
  (void)in_sizes; (void)n_in; (void)out_size; (void)ws_size;
  const float* q_in = (const float*)d_in[0];
  const float* k_in = (const float*)d_in[1];
  const float* v_in = (const float*)d_in[2];
  const float* Wq_w = (const float*)d_in[3];
  const float* Wq_b = (const float*)d_in[4];
  const float* Wk_w = (const float*)d_in[5];
  const float* Wk_b = (const float*)d_in[6];
  const float* Wv_w = (const float*)d_in[7];
  const float* Wv_b = (const float*)d_in[8];
  const float* Wo_w = (const float*)d_in[9];
  const float* Wo_b = (const float*)d_in[10];
  const float* Wp_w = (const float*)d_in[11];
  const float* Wp_b = (const float*)d_in[12];

  char* ws = (char*)d_ws;
  u16* xq    = (u16*)(ws + 0);         // 8 MB  bf16 q_in
  u16* xk    = (u16*)(ws + 8388608);   // 8 MB
  u16* xv    = (u16*)(ws + 16777216);  // 8 MB
  u16* wq    = (u16*)(ws + 25165824);  // 512 KB each
  u16* wk    = (u16*)(ws + 25690112);
  u16* wv    = (u16*)(ws + 26214400);
  u16* wo    = (u16*)(ws + 26738688);
  u16* wp    = (u16*)(ws + 27262976);  // 4096x64 bf16 (row 4095 zero)
  u16* q_ws  = (u16*)(ws + 27787264);  // (b,h,l,d) bf16, pre-scaled log2e/8
  u16* k_ws  = (u16*)(ws + 36175872);
  u16* v_ws  = (u16*)(ws + 44564480);
  u16* opre  = (u16*)(ws + 52953088);  // (b*l, h*d) bf16 diag-scaled v

  prep_kernel<<<6784, 256, 0, stream>>>(q_in, k_in, v_in, Wq_w, Wk_w, Wv_w, Wo_w, Wp_w,
                                        xq, xk, xv, wq, wk, wv, wo, wp);
  qkv_gemm<<<3072, 256, 0, stream>>>(xq, xk, xv, wq, wk, wv, Wq_b, Wk_b, Wv_b,
                                     q_ws, k_ws, v_ws);
  attn_kernel<<<1024, 256, 0, stream>>>(q_ws, k_ws, v_ws, wp, Wp_b, opre);
  gemm_bt<<<1024, 256, 0, stream>>>(opre, wo, Wo_b, (float*)d_out);
}